// Round 1
// baseline (8623.893 us; speedup 1.0000x reference)
//
#include <hip/hip_runtime.h>
#include <math.h>
#include <stdint.h>

// Problem constants (Qwen3-MoE block)
constexpr int Bc = 2, Sc = 2048, Hc = 2048, Ec = 64, Kc = 8, Ic = 768;
constexpr int Tc  = Bc * Sc;   // 4096 tokens
constexpr int TKc = Tc * Kc;   // 32768 dispatched rows

typedef __attribute__((ext_vector_type(8))) short          bf16x8;  // MFMA A/B frag (8 bf16)
typedef __attribute__((ext_vector_type(4))) short          s16x4;   // 8B LDS write unit
typedef __attribute__((ext_vector_type(8))) unsigned short u16x8;   // 16B bf16 load unit
typedef __attribute__((ext_vector_type(4))) float          f32x4;   // MFMA acc frag

// XOR swizzle for [rows][32 bf16] (64B-row) LDS planes: spreads frag-read start
// banks across 8 distinct 16B slots per 8 rows (guide §6 G4 recipe).
#define SWZ(b) ((b) ^ ((((b) >> 6) & 7) << 4))

__device__ __forceinline__ unsigned short bf_hi(float f) {
    unsigned u = __float_as_uint(f);
    u += 0x7fffu + ((u >> 16) & 1u);          // RNE
    return (unsigned short)(u >> 16);
}
__device__ __forceinline__ void bf_split(float f, short& h, short& l) {
    unsigned short hb = bf_hi(f);
    float rem = f - __uint_as_float((unsigned)hb << 16);
    h = (short)hb;
    l = (short)bf_hi(rem);
}
__device__ __forceinline__ float fc(const float4& v, int j) {
    switch (j) { case 0: return v.x; case 1: return v.y; case 2: return v.z; default: return v.w; }
}
__device__ __forceinline__ f32x4 mma16(bf16x8 a, bf16x8 b, f32x4 c) {
    return __builtin_amdgcn_mfma_f32_16x16x32_bf16(a, b, c, 0, 0, 0);
}

// ---------------------------------------------------------------------------
// Router: logits = x @ gw^T, softmax-top8 (renormalized), count tokens/expert
// ---------------------------------------------------------------------------
__global__ __launch_bounds__(256) void router_topk(
    const float* __restrict__ x, const float* __restrict__ gw,
    int* __restrict__ topk_idx, float* __restrict__ topk_w,
    int* __restrict__ counts)
{
    __shared__ float xs[Hc];
    __shared__ float lg[Ec];
    const int t   = blockIdx.x;
    const int tid = threadIdx.x;

    {
        const float4* src = (const float4*)(x + (size_t)t * Hc);
        float4* dst = (float4*)xs;
        dst[tid * 2]     = src[tid * 2];
        dst[tid * 2 + 1] = src[tid * 2 + 1];
    }
    __syncthreads();

    const int wave = tid >> 6, lane = tid & 63;
    for (int j = 0; j < 16; ++j) {
        const int e = wave * 16 + j;
        const float* gr = gw + (size_t)e * Hc;
        float p = 0.f;
        for (int i = lane; i < Hc; i += 64) p += xs[i] * gr[i];
        for (int off = 32; off; off >>= 1) p += __shfl_down(p, off);
        if (lane == 0) lg[e] = p;
    }
    __syncthreads();

    if (tid < 64) {
        float v = lg[lane];
        int   id = lane;
        float sval[8]; int sid[8];
        for (int k = 0; k < 8; ++k) {
            float bv = v; int bi = id;
            for (int off = 32; off; off >>= 1) {
                float ov = __shfl_down(bv, off);
                int   oi = __shfl_down(bi, off);
                if (ov > bv || (ov == bv && oi < bi)) { bv = ov; bi = oi; }
            }
            bv = __shfl(bv, 0); bi = __shfl(bi, 0);
            sval[k] = bv; sid[k] = bi;
            if (id == bi) v = -INFINITY;
        }
        if (lane == 0) {
            float m = sval[0], s = 0.f, w[8];
            for (int k = 0; k < 8; ++k) { w[k] = expf(sval[k] - m); s += w[k]; }
            const float inv = 1.f / s;
            for (int k = 0; k < 8; ++k) {
                topk_idx[t * 8 + k] = sid[k];
                topk_w[t * 8 + k]   = w[k] * inv;
                atomicAdd(&counts[sid[k]], 1);
            }
        }
    }
}

__global__ void prefix_scan(const int* __restrict__ counts, int* __restrict__ offsets)
{
    if (threadIdx.x == 0 && blockIdx.x == 0) {
        int s = 0;
        for (int e = 0; e < Ec; ++e) { offsets[e] = s; s += counts[e]; }
        offsets[Ec] = s;
    }
}

__global__ __launch_bounds__(256) void scatter_rows(
    const int* __restrict__ topk_idx, const int* __restrict__ offsets,
    int* __restrict__ cursor, int* __restrict__ rowtok)
{
    const int idx = blockIdx.x * 256 + threadIdx.x;
    if (idx < TKc) {
        const int e   = topk_idx[idx];
        const int pos = offsets[e] + atomicAdd(&cursor[e], 1);
        rowtok[pos] = idx;
    }
}

// ---------------------------------------------------------------------------
// Grouped GEMM 1 (MFMA, split-bf16): act = silu(x@Wg) * (x@Wu)
// Tile 128 rows x 128 cols, BK=32, 4 waves (2x2), wave tile 64x64 per tensor.
// Split-3: acc += Ahi*Bhi + Alo*Bhi + Ahi*Blo  (fp32-grade accuracy).
// grid = (row-tile 32, n-tile 6, expert 64) so same-panel blocks are adjacent.
// ---------------------------------------------------------------------------
__global__ __launch_bounds__(256, 2) void gemm_act(
    const float* __restrict__ x, const float* __restrict__ wg,
    const float* __restrict__ wu, const int* __restrict__ offsets,
    const int* __restrict__ rowtok,
    unsigned short* __restrict__ act_hi, unsigned short* __restrict__ act_lo)
{
    __shared__ __align__(16) short Ah[128*32], Al[128*32];
    __shared__ __align__(16) short Gh[128*32], Gl[128*32];
    __shared__ __align__(16) short Uh[128*32], Ul[128*32];

    const int e    = blockIdx.z;
    const int base = offsets[e];
    const int M    = offsets[e + 1] - base;
    const int row0 = blockIdx.x * 128;
    if (row0 >= M) return;
    const int n0  = blockIdx.y * 128;
    const int tid = threadIdx.x;

    // A staging: thread -> (row ar, k-half ak)
    const int ar = tid >> 1;
    const int ak = (tid & 1) * 16;
    int ridx = base + row0 + ar;
    if (ridx > TKc - 1) ridx = TKc - 1;           // clamp (padding rows)
    const int tok = rowtok[ridx] >> 3;
    const float* aptr = x + (size_t)tok * Hc + ak;

    // B staging: thread -> (n-quad bq, k-quad bk); 4x4 in-register transpose
    const int bq = (tid >> 3) * 4;                // 0..124
    const int bk = (tid & 7) * 4;                 // 0..28
    const float* gptr = wg + (size_t)e * Hc * Ic + (size_t)bk * Ic + (n0 + bq);
    const float* uptr = wu + (size_t)e * Hc * Ic + (size_t)bk * Ic + (n0 + bq);

    const int lane = tid & 63, wave = tid >> 6;
    const int wm = wave >> 1, wn = wave & 1;
    const int l15 = lane & 15, lk = lane >> 4;

    int aoff[4], boff[4];
    #pragma unroll
    for (int m = 0; m < 4; ++m) aoff[m] = SWZ((wm*64 + m*16 + l15) * 64 + lk*16);
    #pragma unroll
    for (int n = 0; n < 4; ++n) boff[n] = SWZ((wn*64 + n*16 + l15) * 64 + lk*16);

    f32x4 accg[4][4] = {}, accu[4][4] = {};

    float4 ra[4], rg[4], ru[4];
    #pragma unroll
    for (int i = 0; i < 4; ++i) ra[i] = *(const float4*)(aptr + i*4);
    #pragma unroll
    for (int i = 0; i < 4; ++i) rg[i] = *(const float4*)(gptr + (size_t)i * Ic);
    #pragma unroll
    for (int i = 0; i < 4; ++i) ru[i] = *(const float4*)(uptr + (size_t)i * Ic);

    for (int h0 = 0; h0 < Hc; h0 += 32) {
        __syncthreads();   // all waves done reading previous tile

        // ---- convert + stage A (two b128 writes per plane) ----
        {
            const int b0 = ar*64 + ak*2;
            #pragma unroll
            for (int q = 0; q < 2; ++q) {
                bf16x8 vh, vl;
                #pragma unroll
                for (int i = 0; i < 2; ++i)
                    #pragma unroll
                    for (int j = 0; j < 4; ++j) {
                        short h, l; bf_split(fc(ra[q*2 + i], j), h, l);
                        vh[i*4 + j] = h; vl[i*4 + j] = l;
                    }
                *(bf16x8*)((char*)Ah + SWZ(b0 + q*16)) = vh;
                *(bf16x8*)((char*)Al + SWZ(b0 + q*16)) = vl;
            }
        }
        // ---- convert + stage B (wg, wu) with 4x4 transpose ----
        #pragma unroll
        for (int j = 0; j < 4; ++j) {
            const int b = (bq + j)*64 + bk*2;
            s16x4 gh, gl, uh, ul;
            #pragma unroll
            for (int i = 0; i < 4; ++i) {
                short h, l;
                bf_split(fc(rg[i], j), h, l); gh[i] = h; gl[i] = l;
                bf_split(fc(ru[i], j), h, l); uh[i] = h; ul[i] = l;
            }
            *(s16x4*)((char*)Gh + SWZ(b)) = gh;
            *(s16x4*)((char*)Gl + SWZ(b)) = gl;
            *(s16x4*)((char*)Uh + SWZ(b)) = uh;
            *(s16x4*)((char*)Ul + SWZ(b)) = ul;
        }

        // ---- issue next-tile global loads (in flight under MFMA phase) ----
        if (h0 + 32 < Hc) {
            #pragma unroll
            for (int i = 0; i < 4; ++i) ra[i] = *(const float4*)(aptr + (h0 + 32) + i*4);
            #pragma unroll
            for (int i = 0; i < 4; ++i) rg[i] = *(const float4*)(gptr + (size_t)(h0 + 32 + i) * Ic);
            #pragma unroll
            for (int i = 0; i < 4; ++i) ru[i] = *(const float4*)(uptr + (size_t)(h0 + 32 + i) * Ic);
        }

        __syncthreads();   // tile visible

        bf16x8 fah[4], fal[4];
        #pragma unroll
        for (int m = 0; m < 4; ++m) {
            fah[m] = *(const bf16x8*)((const char*)Ah + aoff[m]);
            fal[m] = *(const bf16x8*)((const char*)Al + aoff[m]);
        }
        #pragma unroll
        for (int n = 0; n < 4; ++n) {
            bf16x8 bh = *(const bf16x8*)((const char*)Gh + boff[n]);
            bf16x8 bl = *(const bf16x8*)((const char*)Gl + boff[n]);
            #pragma unroll
            for (int m = 0; m < 4; ++m) {
                accg[m][n] = mma16(fah[m], bh, accg[m][n]);
                accg[m][n] = mma16(fal[m], bh, accg[m][n]);
                accg[m][n] = mma16(fah[m], bl, accg[m][n]);
            }
            bh = *(const bf16x8*)((const char*)Uh + boff[n]);
            bl = *(const bf16x8*)((const char*)Ul + boff[n]);
            #pragma unroll
            for (int m = 0; m < 4; ++m) {
                accu[m][n] = mma16(fah[m], bh, accu[m][n]);
                accu[m][n] = mma16(fal[m], bh, accu[m][n]);
                accu[m][n] = mma16(fah[m], bl, accu[m][n]);
            }
        }
    }

    // epilogue: act = silu(g)*u, stored as bf16 hi/lo planes
    // D layout: col = lane&15, row = (lane>>4)*4 + reg  [m89-verified]
    #pragma unroll
    for (int m = 0; m < 4; ++m) {
        #pragma unroll
        for (int r = 0; r < 4; ++r) {
            const int rl = wm*64 + m*16 + lk*4 + r;
            if (row0 + rl < M) {
                unsigned short* oh = act_hi + (size_t)(base + row0 + rl) * Ic + n0;
                unsigned short* ol = act_lo + (size_t)(base + row0 + rl) * Ic + n0;
                #pragma unroll
                for (int n = 0; n < 4; ++n) {
                    const int c = wn*64 + n*16 + l15;
                    const float g = accg[m][n][r];
                    const float u = accu[m][n][r];
                    const float s = (g / (1.f + expf(-g))) * u;
                    short h, l; bf_split(s, h, l);
                    oh[c] = (unsigned short)h;
                    ol[c] = (unsigned short)l;
                }
            }
        }
    }
}

// ---------------------------------------------------------------------------
// Grouped GEMM 2 (MFMA, split-bf16): out[t] += w_{t,k} * (act @ Wd)
// Tile 128 rows x 256 cols, BK=32, 4 waves (2x2), wave tile 64x128.
// A (act) is already bf16 hi/lo -> zero-conversion staging.
// ---------------------------------------------------------------------------
__global__ __launch_bounds__(256, 2) void gemm_down(
    const unsigned short* __restrict__ act_hi, const unsigned short* __restrict__ act_lo,
    const float* __restrict__ wd, const int* __restrict__ offsets,
    const int* __restrict__ rowtok, const float* __restrict__ topk_w,
    float* __restrict__ out)
{
    __shared__ __align__(16) short Ah[128*32], Al[128*32];
    __shared__ __align__(16) short Bh[256*32], Bl[256*32];

    const int e    = blockIdx.z;
    const int base = offsets[e];
    const int M    = offsets[e + 1] - base;
    const int row0 = blockIdx.x * 128;
    if (row0 >= M) return;
    const int n0  = blockIdx.y * 256;
    const int tid = threadIdx.x;

    const int ar = tid >> 1;
    const int ak = (tid & 1) * 16;
    int ridx = base + row0 + ar;
    if (ridx > TKc - 1) ridx = TKc - 1;
    const unsigned short* ahp = act_hi + (size_t)ridx * Ic + ak;
    const unsigned short* alp = act_lo + (size_t)ridx * Ic + ak;

    const int bq = (tid >> 3) * 4;                // 0..124 (+128 on pass 1)
    const int bk = (tid & 7) * 4;                 // 0..28
    const float* bptr = wd + (size_t)e * Ic * Hc + (size_t)bk * Hc + (n0 + bq);

    const int lane = tid & 63, wave = tid >> 6;
    const int wm = wave >> 1, wn = wave & 1;
    const int l15 = lane & 15, lk = lane >> 4;

    int aoff[4], boff[8];
    #pragma unroll
    for (int m = 0; m < 4; ++m) aoff[m] = SWZ((wm*64 + m*16 + l15) * 64 + lk*16);
    #pragma unroll
    for (int n = 0; n < 8; ++n) boff[n] = SWZ((wn*128 + n*16 + l15) * 64 + lk*16);

    f32x4 acc[4][8] = {};

    u16x8 rah[2], ral[2];
    float4 rb[2][4];
    #pragma unroll
    for (int q = 0; q < 2; ++q) {
        rah[q] = *(const u16x8*)(ahp + q*8);
        ral[q] = *(const u16x8*)(alp + q*8);
    }
    #pragma unroll
    for (int p = 0; p < 2; ++p)
        #pragma unroll
        for (int i = 0; i < 4; ++i)
            rb[p][i] = *(const float4*)(bptr + (size_t)i * Hc + p*128);

    for (int i0 = 0; i0 < Ic; i0 += 32) {
        __syncthreads();

        // A: direct bf16 copy (swizzled b128 writes)
        {
            const int b0 = ar*64 + ak*2;
            *(u16x8*)((char*)Ah + SWZ(b0))      = rah[0];
            *(u16x8*)((char*)Ah + SWZ(b0 + 16)) = rah[1];
            *(u16x8*)((char*)Al + SWZ(b0))      = ral[0];
            *(u16x8*)((char*)Al + SWZ(b0 + 16)) = ral[1];
        }
        // B: convert + 4x4 transpose, two n-passes
        #pragma unroll
        for (int p = 0; p < 2; ++p)
            #pragma unroll
            for (int j = 0; j < 4; ++j) {
                const int b = (bq + p*128 + j)*64 + bk*2;
                s16x4 vh, vl;
                #pragma unroll
                for (int i = 0; i < 4; ++i) {
                    short h, l; bf_split(fc(rb[p][i], j), h, l);
                    vh[i] = h; vl[i] = l;
                }
                *(s16x4*)((char*)Bh + SWZ(b)) = vh;
                *(s16x4*)((char*)Bl + SWZ(b)) = vl;
            }

        if (i0 + 32 < Ic) {
            #pragma unroll
            for (int q = 0; q < 2; ++q) {
                rah[q] = *(const u16x8*)(ahp + (i0 + 32) + q*8);
                ral[q] = *(const u16x8*)(alp + (i0 + 32) + q*8);
            }
            #pragma unroll
            for (int p = 0; p < 2; ++p)
                #pragma unroll
                for (int i = 0; i < 4; ++i)
                    rb[p][i] = *(const float4*)(bptr + (size_t)(i0 + 32 + i) * Hc + p*128);
        }

        __syncthreads();

        bf16x8 fah[4], fal[4];
        #pragma unroll
        for (int m = 0; m < 4; ++m) {
            fah[m] = *(const bf16x8*)((const char*)Ah + aoff[m]);
            fal[m] = *(const bf16x8*)((const char*)Al + aoff[m]);
        }
        #pragma unroll
        for (int n = 0; n < 8; ++n) {
            bf16x8 bh = *(const bf16x8*)((const char*)Bh + boff[n]);
            bf16x8 bl = *(const bf16x8*)((const char*)Bl + boff[n]);
            #pragma unroll
            for (int m = 0; m < 4; ++m) {
                acc[m][n] = mma16(fah[m], bh, acc[m][n]);
                acc[m][n] = mma16(fal[m], bh, acc[m][n]);
                acc[m][n] = mma16(fah[m], bl, acc[m][n]);
            }
        }
    }

    // epilogue: weighted atomic combine
    #pragma unroll
    for (int m = 0; m < 4; ++m) {
        #pragma unroll
        for (int r = 0; r < 4; ++r) {
            const int rl = wm*64 + m*16 + lk*4 + r;
            if (row0 + rl < M) {
                const int idx = rowtok[base + row0 + rl];
                const int t   = idx >> 3;
                const float w = topk_w[idx];
                float* orow = out + (size_t)t * Hc + n0;
                #pragma unroll
                for (int n = 0; n < 8; ++n) {
                    const int c = wn*128 + n*16 + l15;
                    atomicAdd(&orow[c], w * acc[m][n][r]);
                }
            }
        }
    }
}

// ---------------------------------------------------------------------------
extern "C" void kernel_launch(void* const* d_in, const int* in_sizes, int n_in,
                              void* d_out, int out_size, void* d_ws, size_t ws_size,
                              hipStream_t stream)
{
    const float* x  = (const float*)d_in[0];   // [B,S,H]
    const float* gw = (const float*)d_in[1];   // [E,H]
    const float* wg = (const float*)d_in[2];   // [E,H,I]
    const float* wu = (const float*)d_in[3];   // [E,H,I]
    const float* wd = (const float*)d_in[4];   // [E,I,H]
    float* out = (float*)d_out;                // [B,S,H]

    // workspace layout (4B words)
    int*   topk_idx = (int*)d_ws;                       // TKc
    float* topk_wv  = (float*)(topk_idx + TKc);         // TKc
    int*   counts   = (int*)(topk_wv + TKc);            // Ec
    int*   offsets  = counts + Ec;                      // Ec+1
    int*   cursor   = offsets + Ec + 1;                 // Ec
    int*   rowtok   = cursor + Ec;                      // TKc
    unsigned short* act_hi = (unsigned short*)((((uintptr_t)(rowtok + TKc)) + 255) & ~(uintptr_t)255);
    unsigned short* act_lo = act_hi + (size_t)TKc * Ic;  // total act planes = TKc*Ic*4B (same as old fp32 act)

    hipMemsetAsync(counts, 0, (size_t)(3 * Ec + 1) * sizeof(int), stream);
    hipMemsetAsync(out, 0, (size_t)out_size * sizeof(float), stream);

    router_topk<<<Tc, 256, 0, stream>>>(x, gw, topk_idx, topk_wv, counts);
    prefix_scan<<<1, 64, 0, stream>>>(counts, offsets);
    scatter_rows<<<TKc / 256, 256, 0, stream>>>(topk_idx, offsets, cursor, rowtok);
    // grid: x = row-tile (fastest -> same weight panel stays in L2), y = n-tile, z = expert
    gemm_act<<<dim3(32, Ic / 128, Ec), 256, 0, stream>>>(x, wg, wu, offsets, rowtok, act_hi, act_lo);
    gemm_down<<<dim3(32, Hc / 256, Ec), 256, 0, stream>>>(act_hi, act_lo, wd, offsets, rowtok, topk_wv, out);
}